// Round 2
// baseline (366.744 us; speedup 1.0000x reference)
//
#include <hip/hip_runtime.h>
#include <hip/hip_bf16.h>
#include <cstdint>

// Problem: B=4, T=2048, D=1024, H=16, HD=64.
// d_out = [ out (4,2048,1024) | k (4,16,2048,64) | v (4,16,2048,64) ] fp32.

typedef short bf16x8 __attribute__((ext_vector_type(8)));
typedef float f32x4 __attribute__((ext_vector_type(4)));

#define GLDS16(g, l)                                                          \
  __builtin_amdgcn_global_load_lds(                                           \
      (const __attribute__((address_space(1))) void*)(g),                     \
      (__attribute__((address_space(3))) void*)(l), 16, 0, 0)

static __device__ __forceinline__ short f2b(float f) {
  union { float f; unsigned u; } x; x.f = f;
  unsigned r = (x.u + 0x7FFFu + ((x.u >> 16) & 1u)) >> 16;   // RNE
  return (short)r;
}

// single-instruction packed f32->bf16 RNE: dst.lo = a, dst.hi = b
static __device__ __forceinline__ unsigned cvtpk2(float a, float b) {
  unsigned r;
  asm("v_cvt_pk_bf16_f32 %0, %1, %2" : "=v"(r) : "v"(a), "v"(b));
  return r;
}

__global__ void cvt_f32_bf16(const float* __restrict__ src, short* __restrict__ dst, int n4) {
  int i = blockIdx.x * blockDim.x + threadIdx.x;
  if (i < n4) {
    float4 v = ((const float4*)src)[i];
    short4 o; o.x = f2b(v.x); o.y = f2b(v.y); o.z = f2b(v.z); o.w = f2b(v.w);
    ((short4*)dst)[i] = o;
  }
}

// All four weight matrices in one launch (dsts are contiguous in ws).
__global__ void cvt_w4(const float* __restrict__ a, const float* __restrict__ b,
                       const float* __restrict__ c, const float* __restrict__ d,
                       short* __restrict__ dst) {
  int i = blockIdx.x * blockDim.x + threadIdx.x;          // 0..1048575 float4 groups
  int sel = i >> 18, j = i & 262143;
  const float* src = sel == 0 ? a : sel == 1 ? b : sel == 2 ? c : d;
  float4 v = ((const float4*)src)[j];
  short4 o; o.x = f2b(v.x); o.y = f2b(v.y); o.z = f2b(v.z); o.w = f2b(v.w);
  ((short4*)dst)[i] = o;
}

// Staging macro shared by the GEMM kernels: 4x global_load_lds width-16 into
// double buffer `buf` at K-offset kk.
#define STAGE_G(buf, kk)                                                      \
  do {                                                                        \
    GLDS16(Abase + (size_t)r0 * 1024 + (kk) + cc0 * 8, &As[buf][c0 * 8]);     \
    GLDS16(Abase + (size_t)r1 * 1024 + (kk) + cc1 * 8, &As[buf][c1 * 8]);     \
    GLDS16(Bbase + (size_t)r0 * 1024 + (kk) + cc0 * 8, &Bs[buf][c0 * 8]);     \
    GLDS16(Bbase + (size_t)r1 * 1024 + (kk) + cc1 * 8, &Bs[buf][c1 * 8]);     \
  } while (0)

// C[M=8192][N=1024] = A[8192][1024] @ Bm[1024][1024]^T + bias, bf16 MFMA.
// T3-minimum 2-phase double-buffered K-loop: stage tile t+1 before computing
// tile t; the single __syncthreads per iteration drains vmcnt AFTER the MFMAs
// have covered most of the HBM latency (was: full drain between stage and
// compute -> zero overlap). LDS 2x16KB = 32KB, still 4 blocks/CU (VGPR cap).
// Used for the output projection (MODE 3) only.
template <int MODE>
__global__ __launch_bounds__(256) void gemm_bt(
    const short* __restrict__ A, const short* __restrict__ Bm,
    const float* __restrict__ bias,
    float* __restrict__ out_f, short* __restrict__ out_b) {
  __shared__ short As[2][128 * 32];
  __shared__ short Bs[2][128 * 32];
  const int t = threadIdx.x;
  const int lane = t & 63;
  const int w = t >> 6;
  const int wm = w >> 1, wn = w & 1;
  const int quad = lane >> 4, l15 = lane & 15;
  const int bm = blockIdx.y, bn = blockIdx.x;

  f32x4 acc[4][4];
  for (int i = 0; i < 4; i++)
    for (int j = 0; j < 4; j++) acc[i][j] = (f32x4){0.f, 0.f, 0.f, 0.f};

  const int c0 = t, c1 = t + 256;
  const int r0 = c0 >> 2, cc0 = c0 & 3;
  const int r1 = c1 >> 2, cc1 = c1 & 3;
  const short* Abase = A + (size_t)bm * 128 * 1024;
  const short* Bbase = Bm + (size_t)bn * 128 * 1024;

  auto compute = [&](int buf) {
    bf16x8 af[4], bfr[4];
    for (int mt = 0; mt < 4; mt++)
      af[mt] = *(const bf16x8*)(&As[buf][(wm * 64 + mt * 16 + l15) * 32 + quad * 8]);
    for (int nt = 0; nt < 4; nt++)
      bfr[nt] = *(const bf16x8*)(&Bs[buf][(wn * 64 + nt * 16 + l15) * 32 + quad * 8]);
    for (int mt = 0; mt < 4; mt++)
      for (int nt = 0; nt < 4; nt++)
        acc[mt][nt] = __builtin_amdgcn_mfma_f32_16x16x32_bf16(af[mt], bfr[nt], acc[mt][nt], 0, 0, 0);
  };

  STAGE_G(0, 0);
  __syncthreads();   // tile 0 staged (implicit vmcnt(0))
  int cur = 0;
  for (int kk = 32; kk < 1024; kk += 32) {
    STAGE_G(cur ^ 1, kk);   // issue next tile's loads first
    compute(cur);           // MFMA on current tile covers the load latency
    __syncthreads();        // next tile staged + all readers of cur done
    cur ^= 1;
  }
  compute(cur);             // last tile, no prefetch

  for (int mt = 0; mt < 4; mt++) {
    const int row_base = bm * 128 + wm * 64 + mt * 16 + quad * 4;
    for (int nt = 0; nt < 4; nt++) {
      const int col = bn * 128 + wn * 64 + nt * 16 + l15;
      const float bb = bias[col];
      for (int r = 0; r < 4; r++) {
        const int row = row_base + r;
        const float v = acc[mt][nt][r] + bb;
        if (MODE == 3) {
          out_f[(size_t)row * 1024 + col] = v;
        } else {
          const int b = row >> 11, tt = row & 2047;
          const int h = col >> 6, hi = col & 63;
          const size_t idx = (((size_t)(b * 16 + h)) * 2048 + tt) * 64 + hi;
          if (MODE == 0) {
            out_b[idx] = f2b(v);
          } else if (MODE == 1) {
            out_f[idx] = v; out_b[idx] = f2b(v);
          } else {
            out_f[idx] = v;
            out_b[(((size_t)(b * 16 + h)) * 64 + hi) * 2048 + tt] = f2b(v);
          }
        }
      }
    }
  }
}

// Fused Q/K/V projection, same 2-phase double-buffered K-loop.
// blockIdx.x 0..7 -> Q, 8..15 -> K, 16..23 -> V (block-uniform branch).
__global__ __launch_bounds__(256) void gemm_qkv(
    const short* __restrict__ A,
    const short* __restrict__ W0, const short* __restrict__ W1, const short* __restrict__ W2,
    const float* __restrict__ b0, const float* __restrict__ b1, const float* __restrict__ b2,
    float* __restrict__ kf, float* __restrict__ vf,
    short* __restrict__ qbo, short* __restrict__ kbo, short* __restrict__ vtbo) {
  __shared__ short As[2][128 * 32];
  __shared__ short Bs[2][128 * 32];
  const int t = threadIdx.x;
  const int lane = t & 63;
  const int w = t >> 6;
  const int wm = w >> 1, wn = w & 1;
  const int quad = lane >> 4, l15 = lane & 15;
  const int bm = blockIdx.y;
  const int sel = blockIdx.x >> 3, bn = blockIdx.x & 7;
  const short* Bm = sel == 0 ? W0 : (sel == 1 ? W1 : W2);
  const float* bias = sel == 0 ? b0 : (sel == 1 ? b1 : b2);

  f32x4 acc[4][4];
  for (int i = 0; i < 4; i++)
    for (int j = 0; j < 4; j++) acc[i][j] = (f32x4){0.f, 0.f, 0.f, 0.f};

  const int c0 = t, c1 = t + 256;
  const int r0 = c0 >> 2, cc0 = c0 & 3;
  const int r1 = c1 >> 2, cc1 = c1 & 3;
  const short* Abase = A + (size_t)bm * 128 * 1024;
  const short* Bbase = Bm + (size_t)bn * 128 * 1024;

  auto compute = [&](int buf) {
    bf16x8 af[4], bfr[4];
    for (int mt = 0; mt < 4; mt++)
      af[mt] = *(const bf16x8*)(&As[buf][(wm * 64 + mt * 16 + l15) * 32 + quad * 8]);
    for (int nt = 0; nt < 4; nt++)
      bfr[nt] = *(const bf16x8*)(&Bs[buf][(wn * 64 + nt * 16 + l15) * 32 + quad * 8]);
    for (int mt = 0; mt < 4; mt++)
      for (int nt = 0; nt < 4; nt++)
        acc[mt][nt] = __builtin_amdgcn_mfma_f32_16x16x32_bf16(af[mt], bfr[nt], acc[mt][nt], 0, 0, 0);
  };

  STAGE_G(0, 0);
  __syncthreads();
  int cur = 0;
  for (int kk = 32; kk < 1024; kk += 32) {
    STAGE_G(cur ^ 1, kk);
    compute(cur);
    __syncthreads();
    cur ^= 1;
  }
  compute(cur);

  for (int mt = 0; mt < 4; mt++) {
    const int row_base = bm * 128 + wm * 64 + mt * 16 + quad * 4;
    for (int nt = 0; nt < 4; nt++) {
      const int col = bn * 128 + wn * 64 + nt * 16 + l15;
      const float bb = bias[col];
      for (int r = 0; r < 4; r++) {
        const int row = row_base + r;
        const float v = acc[mt][nt][r] + bb;
        const int b = row >> 11, tt = row & 2047;
        const int h = col >> 6, hi = col & 63;
        const size_t idx = (((size_t)(b * 16 + h)) * 2048 + tt) * 64 + hi;
        if (sel == 0) {
          qbo[idx] = f2b(v);
        } else if (sel == 1) {
          kf[idx] = v; kbo[idx] = f2b(v);
        } else {
          vf[idx] = v;
          vtbo[(((size_t)(b * 16 + h)) * 64 + hi) * 2048 + tt] = f2b(v);
        }
      }
    }
  }
}

// Flash attention, S^T form (unchanged from round 1):
//  * Paired causal strips (qt, 31-qt): every block does exactly 17 KV tiles,
//    grid (16,64) = 1024 uniform blocks = exactly 4/CU.
//  * P scratch overlays Ks (one extra __syncthreads orders it); LDS 32768 B.
//  * Softmax on RAW scores, scale folded into exp arg; cvt_pk packing.
//  * Exact defer-rescale (skip O-rescale when alpha==1 for all lanes).
//  * XCD work-remap: XCD k gets a contiguous 8-head range for L2 locality.
__global__ __launch_bounds__(256, 4) void attn_fwd(
    const short* __restrict__ Qb, const short* __restrict__ Kb,
    const short* __restrict__ VTb, short* __restrict__ Ob) {
  __shared__ short Ks[128 * 64];        // 16 KB; doubles as per-wave P after QK barrier
  __shared__ short VTs[64 * 128];       // 16 KB
  const int t = threadIdx.x;
  const int w = t >> 6;
  const int lane = t & 63;
  const int quad = lane >> 4, l15 = lane & 15;

  const int L = blockIdx.x + (blockIdx.y << 4);          // 0..1023
  const int work = ((L & 7) << 7) + (L >> 3);            // XCD k -> bh in [8k,8k+8)
  const int bh = work >> 4;
  const int base = work & 15;
  const int b = bh >> 4, h = bh & 15;

  const short* Qh = Qb + (size_t)bh * 2048 * 64;
  const short* Kh = Kb + (size_t)bh * 2048 * 64;
  const short* VTh = VTb + (size_t)bh * 64 * 2048;
  unsigned* Pd = (unsigned*)Ks + w * 1024;               // wave-private 4 KB
  const int swz = (l15 & 7) << 2;
  const float sscale = 0.125f * 1.4426950408889634f;     // hd^-0.5 * log2(e)

  for (int s = 0; s < 2; ++s) {
    const int qt = s ? (31 - base) : base;               // 17 tiles total per block
    const int q0 = qt * 64 + w * 16;
    const bf16x8 qf0 = *(const bf16x8*)(Qh + (q0 + l15) * 64 + quad * 8);
    const bf16x8 qf1 = *(const bf16x8*)(Qh + (q0 + l15) * 64 + quad * 8 + 32);

    float m_q = -1e30f, l_q = 0.f;
    f32x4 o[4];
    for (int nt = 0; nt < 4; nt++) o[nt] = (f32x4){0.f, 0.f, 0.f, 0.f};
    const int ntile = (qt >> 1) + 1;

    for (int jt = 0; jt < ntile; ++jt) {
      const int j0 = jt << 7;
      __syncthreads();   // previous tile's P/PV readers done
      for (int rr = 0; rr < 4; rr++) {
        const int c = rr * 256 + t;
        const int row = c >> 3, colL = c & 7;
        const int colg = colL ^ (row & 7);
        GLDS16(Kh + (size_t)(j0 + row) * 64 + colg * 8, &Ks[c * 8]);
      }
      for (int rr = 0; rr < 4; rr++) {
        const int c = rr * 256 + t;
        const int row = c >> 4, colL = c & 15;
        const int colg = colL ^ (row & 7);
        GLDS16(VTh + (size_t)row * 2048 + j0 + colg * 8, &VTs[c * 8]);
      }
      __syncthreads();   // staging complete (vmcnt drained)

      float sv[8][4];    // RAW scores (scale folded into exp arg later)
      for (int si = 0; si < 8; ++si) {
        const int r = si * 16 + l15;
        bf16x8 kf0 = *(const bf16x8*)&Ks[(r * 8 + (quad ^ (r & 7))) * 8];
        bf16x8 kf1 = *(const bf16x8*)&Ks[(r * 8 + ((quad ^ 4) ^ (r & 7))) * 8];
        f32x4 z = (f32x4){0.f, 0.f, 0.f, 0.f};
        z = __builtin_amdgcn_mfma_f32_16x16x32_bf16(kf0, qf0, z, 0, 0, 0);
        z = __builtin_amdgcn_mfma_f32_16x16x32_bf16(kf1, qf1, z, 0, 0, 0);
        for (int r4 = 0; r4 < 4; r4++) sv[si][r4] = z[r4];
      }
      if (jt == ntile - 1) {                              // diagonal tile masks
        const int qg = q0 + l15;
        for (int si = 0; si < 8; si++) {
          const int kbase = j0 + si * 16 + quad * 4;
          for (int r4 = 0; r4 < 4; r4++)
            if (kbase + r4 > qg) sv[si][r4] = -1e30f;
        }
      }
      float vmax = fmaxf(fmaxf(sv[0][0], sv[0][1]), fmaxf(sv[0][2], sv[0][3]));
      for (int si = 1; si < 8; si++) {
        float m2 = fmaxf(fmaxf(sv[si][0], sv[si][1]), fmaxf(sv[si][2], sv[si][3]));
        vmax = fmaxf(vmax, m2);
      }
      vmax = fmaxf(vmax, __shfl_xor(vmax, 16));
      vmax = fmaxf(vmax, __shfl_xor(vmax, 32));
      const float mn = fmaxf(m_q, vmax);
      if (__any(vmax > m_q)) {           // exact skip: otherwise alpha==1 for all lanes
        const float alpha = __builtin_amdgcn_exp2f((m_q - mn) * sscale);
        l_q *= alpha;
        float ar[4];
        for (int r4 = 0; r4 < 4; r4++) ar[r4] = __shfl(alpha, quad * 4 + r4);
        for (int nt = 0; nt < 4; nt++)
          for (int r4 = 0; r4 < 4; r4++) o[nt][r4] *= ar[r4];
      }
      m_q = mn;
      __syncthreads();   // all waves done reading Ks -> safe to overlay P

      const float negmns = -mn * sscale;
      float ssum = 0.f;
      for (int si = 0; si < 8; si++) {
        float p0 = __builtin_amdgcn_exp2f(fmaf(sv[si][0], sscale, negmns));
        float p1 = __builtin_amdgcn_exp2f(fmaf(sv[si][1], sscale, negmns));
        float p2 = __builtin_amdgcn_exp2f(fmaf(sv[si][2], sscale, negmns));
        float p3 = __builtin_amdgcn_exp2f(fmaf(sv[si][3], sscale, negmns));
        ssum += (p0 + p1) + (p2 + p3);
        uint2 pk; pk.x = cvtpk2(p0, p1); pk.y = cvtpk2(p2, p3);
        *(uint2*)(Pd + l15 * 64 + ((si * 8 + quad * 2) ^ swz)) = pk;
      }
      ssum += __shfl_xor(ssum, 16);
      ssum += __shfl_xor(ssum, 32);
      l_q += ssum;       // alpha already applied inside the rescale branch

      for (int kc = 0; kc < 4; kc++) {
        bf16x8 pf = *(const bf16x8*)(Pd + l15 * 64 + ((kc * 16 + quad * 4) ^ swz));
        for (int nt = 0; nt < 4; nt++) {
          const int rv = nt * 16 + l15;
          bf16x8 vf = *(const bf16x8*)&VTs[(rv * 16 + ((kc * 4 + quad) ^ (rv & 7))) * 8];
          o[nt] = __builtin_amdgcn_mfma_f32_16x16x32_bf16(pf, vf, o[nt], 0, 0, 0);
        }
      }
    }

    float lr[4], ri[4];
    for (int r4 = 0; r4 < 4; r4++) lr[r4] = __shfl(l_q, quad * 4 + r4);
    for (int r4 = 0; r4 < 4; r4++) ri[r4] = __builtin_amdgcn_rcpf(lr[r4]);
    for (int nt = 0; nt < 4; nt++) {
      const int col = h * 64 + nt * 16 + l15;
      for (int r4 = 0; r4 < 4; r4++) {
        const int q = q0 + quad * 4 + r4;
        Ob[((size_t)b * 2048 + q) * 1024 + col] = f2b(o[nt][r4] * ri[r4]);
      }
    }
  }
}

extern "C" void kernel_launch(void* const* d_in, const int* in_sizes, int n_in,
                              void* d_out, int out_size, void* d_ws, size_t ws_size,
                              hipStream_t stream) {
  const float* x  = (const float*)d_in[0];
  const float* Wq = (const float*)d_in[1];
  const float* bq = (const float*)d_in[2];
  const float* Wk = (const float*)d_in[3];
  const float* bk = (const float*)d_in[4];
  const float* Wv = (const float*)d_in[5];
  const float* bv = (const float*)d_in[6];
  const float* Wo = (const float*)d_in[7];
  const float* bo = (const float*)d_in[8];

  float* out   = (float*)d_out;
  float* k_out = out + (size_t)8388608;
  float* v_out = out + (size_t)16777216;

  short* ws  = (short*)d_ws;
  short* xb   = ws;                    // 8388608 elems
  short* wqb  = ws + 8388608;          // 1048576 (wq,wk,wv,wo contiguous)
  short* wkb  = ws + 9437184;
  short* wvb  = ws + 10485760;
  short* wob  = ws + 11534336;
  short* qb   = ws + 12582912;         // 8388608 [B,H,T,64]
  short* kb   = ws + 20971520;         // 8388608 [B,H,T,64]
  short* vtb  = ws + 29360128;         // 8388608 [B,H,64,T]
  short* attb = ws + 37748736;         // 8388608 [B*T,1024]

  cvt_f32_bf16<<<8192, 256, 0, stream>>>(x, xb, 2097152);
  cvt_w4<<<4096, 256, 0, stream>>>(Wq, Wk, Wv, Wo, wqb);

  gemm_qkv<<<dim3(24, 64), 256, 0, stream>>>(
      xb, wqb, wkb, wvb, bq, bk, bv, k_out, v_out, qb, kb, vtb);

  attn_fwd<<<dim3(16, 64), 256, 0, stream>>>(qb, kb, vtb, attb);

  gemm_bt<3><<<dim3(8, 64), 256, 0, stream>>>(attb, wob, bo, out, nullptr);
}

// Round 4
// 328.617 us; speedup vs baseline: 1.1160x; 1.1160x over previous
//
#include <hip/hip_runtime.h>
#include <hip/hip_bf16.h>
#include <cstdint>

// Problem: B=4, T=2048, D=1024, H=16, HD=64.
// d_out = [ out (4,2048,1024) | k (4,16,2048,64) | v (4,16,2048,64) ] fp32.

typedef short bf16x8 __attribute__((ext_vector_type(8)));
typedef float f32x4 __attribute__((ext_vector_type(4)));

#define GLDS16(g, l)                                                          \
  __builtin_amdgcn_global_load_lds(                                           \
      (const __attribute__((address_space(1))) void*)(g),                     \
      (__attribute__((address_space(3))) void*)(l), 16, 0, 0)

static __device__ __forceinline__ short f2b(float f) {
  union { float f; unsigned u; } x; x.f = f;
  unsigned r = (x.u + 0x7FFFu + ((x.u >> 16) & 1u)) >> 16;   // RNE
  return (short)r;
}

// single-instruction packed f32->bf16 RNE: dst.lo = a, dst.hi = b
static __device__ __forceinline__ unsigned cvtpk2(float a, float b) {
  unsigned r;
  asm("v_cvt_pk_bf16_f32 %0, %1, %2" : "=v"(r) : "v"(a), "v"(b));
  return r;
}

__global__ void cvt_f32_bf16(const float* __restrict__ src, short* __restrict__ dst, int n4) {
  int i = blockIdx.x * blockDim.x + threadIdx.x;
  if (i < n4) {
    float4 v = ((const float4*)src)[i];
    short4 o; o.x = f2b(v.x); o.y = f2b(v.y); o.z = f2b(v.z); o.w = f2b(v.w);
    ((short4*)dst)[i] = o;
  }
}

// All four weight matrices in one launch (dsts are contiguous in ws).
__global__ void cvt_w4(const float* __restrict__ a, const float* __restrict__ b,
                       const float* __restrict__ c, const float* __restrict__ d,
                       short* __restrict__ dst) {
  int i = blockIdx.x * blockDim.x + threadIdx.x;          // 0..1048575 float4 groups
  int sel = i >> 18, j = i & 262143;
  const float* src = sel == 0 ? a : sel == 1 ? b : sel == 2 ? c : d;
  float4 v = ((const float4*)src)[j];
  short4 o; o.x = f2b(v.x); o.y = f2b(v.y); o.z = f2b(v.z); o.w = f2b(v.w);
  ((short4*)dst)[i] = o;
}

// ---------------------------------------------------------------------------
// GEMM core: 128x128 tile, BK=32, 4 waves, T4 counted-vmcnt 3-deep pipeline.
// Per step (tile t, buf = t%3, compile-time constant via x3 unroll):
//   s_waitcnt vmcnt(4) lgkmcnt(0)  -- my tile-t stages landed AND all my LDS
//                                     reads of the buffer being recycled are
//                                     complete (WAR-safe)
//   s_barrier                      -- join all waves (their stages landed too)
//   sched_barrier(0)               -- nothing hoists above the barrier
//   stage tile t+2 (buf (t+2)%3)   -- overwrites buffer read 1 step ago: safe
//   ds_read + 16 MFMA on tile t
// vmcnt never drains to 0 in the main loop (T4: m218/m248 — this is the gain
// of the phase-split schedule). Round-3 bug: without lgkmcnt(0)+sched_barrier
// the compiler could move LDS reads/uses across the raw s_barrier -> race.
// ---------------------------------------------------------------------------
#define PIPE_STEP(BUF)                                                        \
  {                                                                          \
    asm volatile("s_waitcnt vmcnt(4) lgkmcnt(0)" ::: "memory");              \
    __builtin_amdgcn_s_barrier();                                            \
    __builtin_amdgcn_sched_barrier(0);                                       \
    stage((((BUF) + 2) % 3), (tile + 2) * 32);                               \
    compute(BUF);                                                            \
    ++tile;                                                                  \
  }

#define PIPE_TAIL()                                                          \
  asm volatile("s_waitcnt vmcnt(4) lgkmcnt(0)" ::: "memory");                \
  __builtin_amdgcn_s_barrier();                                              \
  __builtin_amdgcn_sched_barrier(0);                                         \
  compute(0); /* tile 30 */                                                  \
  asm volatile("s_waitcnt vmcnt(0) lgkmcnt(0)" ::: "memory");                \
  __builtin_amdgcn_s_barrier();                                              \
  __builtin_amdgcn_sched_barrier(0);                                         \
  compute(1); /* tile 31 */

// Fused Q/K/V projection. blockIdx.x 0..7 -> Q, 8..15 -> K, 16..23 -> V.
// sel==2 (V) epilogue: bf16 transpose to [B,H,64,T] goes through LDS (reusing
// the staging buffers) -> 8x b128 coalesced stores/thread instead of 64x 2B
// scattered stores/thread.
__global__ __launch_bounds__(256) void gemm_qkv(
    const short* __restrict__ A,
    const short* __restrict__ W0, const short* __restrict__ W1, const short* __restrict__ W2,
    const float* __restrict__ b0, const float* __restrict__ b1, const float* __restrict__ b2,
    float* __restrict__ kf, float* __restrict__ vf,
    short* __restrict__ qbo, short* __restrict__ kbo, short* __restrict__ vtbo) {
  __shared__ short SM[24576];                              // 48 KB: A bufs 0..2, B bufs 0..2
  const int t = threadIdx.x;
  const int lane = t & 63;
  const int w = t >> 6;
  const int wm = w >> 1, wn = w & 1;
  const int quad = lane >> 4, l15 = lane & 15;
  const int bm = blockIdx.y;
  const int sel = blockIdx.x >> 3, bn = blockIdx.x & 7;    // block-uniform branch
  const short* Bm = sel == 0 ? W0 : (sel == 1 ? W1 : W2);
  const float* bias = sel == 0 ? b0 : (sel == 1 ? b1 : b2);

  f32x4 acc[4][4];
  for (int i = 0; i < 4; i++)
    for (int j = 0; j < 4; j++) acc[i][j] = (f32x4){0.f, 0.f, 0.f, 0.f};

  const int c0 = t, c1 = t + 256;
  const int r0 = c0 >> 2, cc0 = c0 & 3;
  const int r1 = c1 >> 2, cc1 = c1 & 3;
  const short* Abase = A + (size_t)bm * 128 * 1024;
  const short* Bbase = Bm + (size_t)bn * 128 * 1024;

  auto stage = [&](int buf, int kk) {
    short* A_ = SM + buf * 4096;
    short* B_ = SM + 12288 + buf * 4096;
    GLDS16(Abase + (size_t)r0 * 1024 + kk + cc0 * 8, A_ + c0 * 8);
    GLDS16(Abase + (size_t)r1 * 1024 + kk + cc1 * 8, A_ + c1 * 8);
    GLDS16(Bbase + (size_t)r0 * 1024 + kk + cc0 * 8, B_ + c0 * 8);
    GLDS16(Bbase + (size_t)r1 * 1024 + kk + cc1 * 8, B_ + c1 * 8);
  };
  auto compute = [&](int buf) {
    const short* A_ = SM + buf * 4096;
    const short* B_ = SM + 12288 + buf * 4096;
    bf16x8 af[4], bfr[4];
    for (int mt = 0; mt < 4; mt++)
      af[mt] = *(const bf16x8*)(A_ + (wm * 64 + mt * 16 + l15) * 32 + quad * 8);
    for (int nt = 0; nt < 4; nt++)
      bfr[nt] = *(const bf16x8*)(B_ + (wn * 64 + nt * 16 + l15) * 32 + quad * 8);
    for (int mt = 0; mt < 4; mt++)
      for (int nt = 0; nt < 4; nt++)
        acc[mt][nt] = __builtin_amdgcn_mfma_f32_16x16x32_bf16(af[mt], bfr[nt], acc[mt][nt], 0, 0, 0);
  };

  stage(0, 0);
  stage(1, 32);
  int tile = 0;
  for (int ii = 0; ii < 10; ++ii) {      // tiles 0..29; stages tiles 2..31
    PIPE_STEP(0) PIPE_STEP(1) PIPE_STEP(2)
  }
  PIPE_TAIL()                             // tiles 30, 31

  if (sel != 2) {
    for (int mt = 0; mt < 4; mt++) {
      const int row_base = bm * 128 + wm * 64 + mt * 16 + quad * 4;
      for (int nt = 0; nt < 4; nt++) {
        const int col = bn * 128 + wn * 64 + nt * 16 + l15;
        const float bb = bias[col];
        for (int r = 0; r < 4; r++) {
          const int row = row_base + r;
          const float v = acc[mt][nt][r] + bb;
          const int b = row >> 11, tt = row & 2047;
          const int h = col >> 6, hi = col & 63;
          const size_t idx = (((size_t)(b * 16 + h)) * 2048 + tt) * 64 + hi;
          if (sel == 0) {
            qbo[idx] = f2b(v);
          } else {
            kf[idx] = v; kbo[idx] = f2b(v);
          }
        }
      }
    }
  } else {
    // V path: f32 out direct; bf16 transpose via LDS (stride 136 shorts:
    // 272 B row, 16B-aligned accesses). All staging DMA drained (vmcnt(0) in
    // PIPE_TAIL) and __syncthreads orders all waves' reads before overwrite.
    short* Tr = SM;                       // 128*136*2 = 34816 B <= 48 KB
    __syncthreads();
    for (int mt = 0; mt < 4; mt++) {
      const int rowb = wm * 64 + mt * 16 + quad * 4;     // local row base
      const int growb = bm * 128 + rowb;
      const int b_ = growb >> 11;
      for (int nt = 0; nt < 4; nt++) {
        const int colL = wn * 64 + nt * 16 + l15;
        const int col = bn * 128 + colL;
        const float bb = bias[col];
        const int h_ = col >> 6, hi_ = col & 63;
        short4 pk;
        for (int r = 0; r < 4; r++) {
          const float v = acc[mt][nt][r] + bb;
          const int tt = (growb + r) & 2047;
          vf[(((size_t)(b_ * 16 + h_)) * 2048 + tt) * 64 + hi_] = v;
          ((short*)&pk)[r] = f2b(v);
        }
        *(short4*)&Tr[colL * 136 + rowb] = pk;
      }
    }
    __syncthreads();
    const int c = t & 127, half = t >> 7;
    const int gcol = bn * 128 + c;
    const int h_ = gcol >> 6, hi_ = gcol & 63;
    for (int j = 0; j < 8; j++) {
      const int chunk = half * 8 + j;
      const int row0 = bm * 128 + chunk * 8;
      const int b_ = row0 >> 11, tt = row0 & 2047;
      bf16x8 val = *(const bf16x8*)&Tr[c * 136 + chunk * 8];
      *(bf16x8*)&vtbo[(((size_t)(b_ * 16 + h_)) * 64 + hi_) * 2048 + tt] = val;
    }
  }
}

// Output projection: C[8192][1024] = attb @ Wo^T + bo, same T4 pipeline.
__global__ __launch_bounds__(256) void gemm_o(
    const short* __restrict__ A, const short* __restrict__ Bm,
    const float* __restrict__ bias, float* __restrict__ out_f) {
  __shared__ short SM[24576];
  const int t = threadIdx.x;
  const int lane = t & 63;
  const int w = t >> 6;
  const int wm = w >> 1, wn = w & 1;
  const int quad = lane >> 4, l15 = lane & 15;
  const int bm = blockIdx.y, bn = blockIdx.x;

  f32x4 acc[4][4];
  for (int i = 0; i < 4; i++)
    for (int j = 0; j < 4; j++) acc[i][j] = (f32x4){0.f, 0.f, 0.f, 0.f};

  const int c0 = t, c1 = t + 256;
  const int r0 = c0 >> 2, cc0 = c0 & 3;
  const int r1 = c1 >> 2, cc1 = c1 & 3;
  const short* Abase = A + (size_t)bm * 128 * 1024;
  const short* Bbase = Bm + (size_t)bn * 128 * 1024;

  auto stage = [&](int buf, int kk) {
    short* A_ = SM + buf * 4096;
    short* B_ = SM + 12288 + buf * 4096;
    GLDS16(Abase + (size_t)r0 * 1024 + kk + cc0 * 8, A_ + c0 * 8);
    GLDS16(Abase + (size_t)r1 * 1024 + kk + cc1 * 8, A_ + c1 * 8);
    GLDS16(Bbase + (size_t)r0 * 1024 + kk + cc0 * 8, B_ + c0 * 8);
    GLDS16(Bbase + (size_t)r1 * 1024 + kk + cc1 * 8, B_ + c1 * 8);
  };
  auto compute = [&](int buf) {
    const short* A_ = SM + buf * 4096;
    const short* B_ = SM + 12288 + buf * 4096;
    bf16x8 af[4], bfr[4];
    for (int mt = 0; mt < 4; mt++)
      af[mt] = *(const bf16x8*)(A_ + (wm * 64 + mt * 16 + l15) * 32 + quad * 8);
    for (int nt = 0; nt < 4; nt++)
      bfr[nt] = *(const bf16x8*)(B_ + (wn * 64 + nt * 16 + l15) * 32 + quad * 8);
    for (int mt = 0; mt < 4; mt++)
      for (int nt = 0; nt < 4; nt++)
        acc[mt][nt] = __builtin_amdgcn_mfma_f32_16x16x32_bf16(af[mt], bfr[nt], acc[mt][nt], 0, 0, 0);
  };

  stage(0, 0);
  stage(1, 32);
  int tile = 0;
  for (int ii = 0; ii < 10; ++ii) {
    PIPE_STEP(0) PIPE_STEP(1) PIPE_STEP(2)
  }
  PIPE_TAIL()

  for (int mt = 0; mt < 4; mt++) {
    const int row_base = bm * 128 + wm * 64 + mt * 16 + quad * 4;
    for (int nt = 0; nt < 4; nt++) {
      const int col = bn * 128 + wn * 64 + nt * 16 + l15;
      const float bb = bias[col];
      for (int r = 0; r < 4; r++) {
        const int row = row_base + r;
        out_f[(size_t)row * 1024 + col] = acc[mt][nt][r] + bb;
      }
    }
  }
}

// Flash attention, S^T form (unchanged from rounds 1/2 — verified passing):
//  * Paired causal strips (qt, 31-qt): every block does exactly 17 KV tiles,
//    grid (16,64) = 1024 uniform blocks = exactly 4/CU.
//  * P scratch overlays Ks (one extra __syncthreads orders it); LDS 32768 B.
//  * Softmax on RAW scores, scale folded into exp arg; cvt_pk packing.
//  * Exact defer-rescale (skip O-rescale when alpha==1 for all lanes).
//  * XCD work-remap: XCD k gets a contiguous 8-head range for L2 locality.
__global__ __launch_bounds__(256, 4) void attn_fwd(
    const short* __restrict__ Qb, const short* __restrict__ Kb,
    const short* __restrict__ VTb, short* __restrict__ Ob) {
  __shared__ short Ks[128 * 64];        // 16 KB; doubles as per-wave P after QK barrier
  __shared__ short VTs[64 * 128];       // 16 KB
  const int t = threadIdx.x;
  const int w = t >> 6;
  const int lane = t & 63;
  const int quad = lane >> 4, l15 = lane & 15;

  const int L = blockIdx.x + (blockIdx.y << 4);          // 0..1023
  const int work = ((L & 7) << 7) + (L >> 3);            // XCD k -> bh in [8k,8k+8)
  const int bh = work >> 4;
  const int base = work & 15;
  const int b = bh >> 4, h = bh & 15;

  const short* Qh = Qb + (size_t)bh * 2048 * 64;
  const short* Kh = Kb + (size_t)bh * 2048 * 64;
  const short* VTh = VTb + (size_t)bh * 64 * 2048;
  unsigned* Pd = (unsigned*)Ks + w * 1024;               // wave-private 4 KB
  const int swz = (l15 & 7) << 2;
  const float sscale = 0.125f * 1.4426950408889634f;     // hd^-0.5 * log2(e)

  for (int s = 0; s < 2; ++s) {
    const int qt = s ? (31 - base) : base;               // 17 tiles total per block
    const int q0 = qt * 64 + w * 16;
    const bf16x8 qf0 = *(const bf16x8*)(Qh + (q0 + l15) * 64 + quad * 8);
    const bf16x8 qf1 = *(const bf16x8*)(Qh + (q0 + l15) * 64 + quad * 8 + 32);

    float m_q = -1e30f, l_q = 0.f;
    f32x4 o[4];
    for (int nt = 0; nt < 4; nt++) o[nt] = (f32x4){0.f, 0.f, 0.f, 0.f};
    const int ntile = (qt >> 1) + 1;

    for (int jt = 0; jt < ntile; ++jt) {
      const int j0 = jt << 7;
      __syncthreads();   // previous tile's P/PV readers done
      for (int rr = 0; rr < 4; rr++) {
        const int c = rr * 256 + t;
        const int row = c >> 3, colL = c & 7;
        const int colg = colL ^ (row & 7);
        GLDS16(Kh + (size_t)(j0 + row) * 64 + colg * 8, &Ks[c * 8]);
      }
      for (int rr = 0; rr < 4; rr++) {
        const int c = rr * 256 + t;
        const int row = c >> 4, colL = c & 15;
        const int colg = colL ^ (row & 7);
        GLDS16(VTh + (size_t)row * 2048 + j0 + colg * 8, &VTs[c * 8]);
      }
      __syncthreads();   // staging complete (vmcnt drained)

      float sv[8][4];    // RAW scores (scale folded into exp arg later)
      for (int si = 0; si < 8; ++si) {
        const int r = si * 16 + l15;
        bf16x8 kf0 = *(const bf16x8*)&Ks[(r * 8 + (quad ^ (r & 7))) * 8];
        bf16x8 kf1 = *(const bf16x8*)&Ks[(r * 8 + ((quad ^ 4) ^ (r & 7))) * 8];
        f32x4 z = (f32x4){0.f, 0.f, 0.f, 0.f};
        z = __builtin_amdgcn_mfma_f32_16x16x32_bf16(kf0, qf0, z, 0, 0, 0);
        z = __builtin_amdgcn_mfma_f32_16x16x32_bf16(kf1, qf1, z, 0, 0, 0);
        for (int r4 = 0; r4 < 4; r4++) sv[si][r4] = z[r4];
      }
      if (jt == ntile - 1) {                              // diagonal tile masks
        const int qg = q0 + l15;
        for (int si = 0; si < 8; si++) {
          const int kbase = j0 + si * 16 + quad * 4;
          for (int r4 = 0; r4 < 4; r4++)
            if (kbase + r4 > qg) sv[si][r4] = -1e30f;
        }
      }
      float vmax = fmaxf(fmaxf(sv[0][0], sv[0][1]), fmaxf(sv[0][2], sv[0][3]));
      for (int si = 1; si < 8; si++) {
        float m2 = fmaxf(fmaxf(sv[si][0], sv[si][1]), fmaxf(sv[si][2], sv[si][3]));
        vmax = fmaxf(vmax, m2);
      }
      vmax = fmaxf(vmax, __shfl_xor(vmax, 16));
      vmax = fmaxf(vmax, __shfl_xor(vmax, 32));
      const float mn = fmaxf(m_q, vmax);
      if (__any(vmax > m_q)) {           // exact skip: otherwise alpha==1 for all lanes
        const float alpha = __builtin_amdgcn_exp2f((m_q - mn) * sscale);
        l_q *= alpha;
        float ar[4];
        for (int r4 = 0; r4 < 4; r4++) ar[r4] = __shfl(alpha, quad * 4 + r4);
        for (int nt = 0; nt < 4; nt++)
          for (int r4 = 0; r4 < 4; r4++) o[nt][r4] *= ar[r4];
      }
      m_q = mn;
      __syncthreads();   // all waves done reading Ks -> safe to overlay P

      const float negmns = -mn * sscale;
      float ssum = 0.f;
      for (int si = 0; si < 8; si++) {
        float p0 = __builtin_amdgcn_exp2f(fmaf(sv[si][0], sscale, negmns));
        float p1 = __builtin_amdgcn_exp2f(fmaf(sv[si][1], sscale, negmns));
        float p2 = __builtin_amdgcn_exp2f(fmaf(sv[si][2], sscale, negmns));
        float p3 = __builtin_amdgcn_exp2f(fmaf(sv[si][3], sscale, negmns));
        ssum += (p0 + p1) + (p2 + p3);
        uint2 pk; pk.x = cvtpk2(p0, p1); pk.y = cvtpk2(p2, p3);
        *(uint2*)(Pd + l15 * 64 + ((si * 8 + quad * 2) ^ swz)) = pk;
      }
      ssum += __shfl_xor(ssum, 16);
      ssum += __shfl_xor(ssum, 32);
      l_q += ssum;       // alpha already applied inside the rescale branch

      for (int kc = 0; kc < 4; kc++) {
        bf16x8 pf = *(const bf16x8*)(Pd + l15 * 64 + ((kc * 16 + quad * 4) ^ swz));
        for (int nt = 0; nt < 4; nt++) {
          const int rv = nt * 16 + l15;
          bf16x8 vf = *(const bf16x8*)&VTs[(rv * 16 + ((kc * 4 + quad) ^ (rv & 7))) * 8];
          o[nt] = __builtin_amdgcn_mfma_f32_16x16x32_bf16(pf, vf, o[nt], 0, 0, 0);
        }
      }
    }

    float lr[4], ri[4];
    for (int r4 = 0; r4 < 4; r4++) lr[r4] = __shfl(l_q, quad * 4 + r4);
    for (int r4 = 0; r4 < 4; r4++) ri[r4] = __builtin_amdgcn_rcpf(lr[r4]);
    for (int nt = 0; nt < 4; nt++) {
      const int col = h * 64 + nt * 16 + l15;
      for (int r4 = 0; r4 < 4; r4++) {
        const int q = q0 + quad * 4 + r4;
        Ob[((size_t)b * 2048 + q) * 1024 + col] = f2b(o[nt][r4] * ri[r4]);
      }
    }
  }
}

extern "C" void kernel_launch(void* const* d_in, const int* in_sizes, int n_in,
                              void* d_out, int out_size, void* d_ws, size_t ws_size,
                              hipStream_t stream) {
  const float* x  = (const float*)d_in[0];
  const float* Wq = (const float*)d_in[1];
  const float* bq = (const float*)d_in[2];
  const float* Wk = (const float*)d_in[3];
  const float* bk = (const float*)d_in[4];
  const float* Wv = (const float*)d_in[5];
  const float* bv = (const float*)d_in[6];
  const float* Wo = (const float*)d_in[7];
  const float* bo = (const float*)d_in[8];

  float* out   = (float*)d_out;
  float* k_out = out + (size_t)8388608;
  float* v_out = out + (size_t)16777216;

  short* ws  = (short*)d_ws;
  short* xb   = ws;                    // 8388608 elems
  short* wqb  = ws + 8388608;          // 1048576 (wq,wk,wv,wo contiguous)
  short* wkb  = ws + 9437184;
  short* wvb  = ws + 10485760;
  short* wob  = ws + 11534336;
  short* qb   = ws + 12582912;         // 8388608 [B,H,T,64]
  short* kb   = ws + 20971520;         // 8388608 [B,H,T,64]
  short* vtb  = ws + 29360128;         // 8388608 [B,H,64,T]
  short* attb = ws + 37748736;         // 8388608 [B*T,1024]

  cvt_f32_bf16<<<8192, 256, 0, stream>>>(x, xb, 2097152);
  cvt_w4<<<4096, 256, 0, stream>>>(Wq, Wk, Wv, Wo, wqb);

  gemm_qkv<<<dim3(24, 64), 256, 0, stream>>>(
      xb, wqb, wkb, wvb, bq, bk, bv, k_out, v_out, qb, kb, vtb);

  attn_fwd<<<dim3(16, 64), 256, 0, stream>>>(qb, kb, vtb, attb);

  gemm_o<<<dim3(8, 64), 256, 0, stream>>>(attb, wob, bo, out);
}

// Round 5
// 324.335 us; speedup vs baseline: 1.1308x; 1.0132x over previous
//
#include <hip/hip_runtime.h>
#include <hip/hip_bf16.h>
#include <cstdint>

// Problem: B=4, T=2048, D=1024, H=16, HD=64.
// d_out = [ out (4,2048,1024) | k (4,16,2048,64) | v (4,16,2048,64) ] fp32.

typedef short bf16x8 __attribute__((ext_vector_type(8)));
typedef float f32x4 __attribute__((ext_vector_type(4)));

#define GLDS16(g, l)                                                          \
  __builtin_amdgcn_global_load_lds(                                           \
      (const __attribute__((address_space(1))) void*)(g),                     \
      (__attribute__((address_space(3))) void*)(l), 16, 0, 0)

static __device__ __forceinline__ short f2b(float f) {
  union { float f; unsigned u; } x; x.f = f;
  unsigned r = (x.u + 0x7FFFu + ((x.u >> 16) & 1u)) >> 16;   // RNE
  return (short)r;
}

// single-instruction packed f32->bf16 RNE: dst.lo = a, dst.hi = b
static __device__ __forceinline__ unsigned cvtpk2(float a, float b) {
  unsigned r;
  asm("v_cvt_pk_bf16_f32 %0, %1, %2" : "=v"(r) : "v"(a), "v"(b));
  return r;
}

__global__ void cvt_f32_bf16(const float* __restrict__ src, short* __restrict__ dst, int n4) {
  int i = blockIdx.x * blockDim.x + threadIdx.x;
  if (i < n4) {
    float4 v = ((const float4*)src)[i];
    short4 o; o.x = f2b(v.x); o.y = f2b(v.y); o.z = f2b(v.z); o.w = f2b(v.w);
    ((short4*)dst)[i] = o;
  }
}

// All four weight matrices in one launch (dsts are contiguous in ws).
__global__ void cvt_w4(const float* __restrict__ a, const float* __restrict__ b,
                       const float* __restrict__ c, const float* __restrict__ d,
                       short* __restrict__ dst) {
  int i = blockIdx.x * blockDim.x + threadIdx.x;          // 0..1048575 float4 groups
  int sel = i >> 18, j = i & 262143;
  const float* src = sel == 0 ? a : sel == 1 ? b : sel == 2 ? c : d;
  float4 v = ((const float4*)src)[j];
  short4 o; o.x = f2b(v.x); o.y = f2b(v.y); o.z = f2b(v.z); o.w = f2b(v.w);
  ((short4*)dst)[i] = o;
}

// ---------------------------------------------------------------------------
// GEMM core: 128x128 tile, BK=32, 4 waves, T4 counted-vmcnt 3-deep pipeline.
// (verified passing, round 4)
// ---------------------------------------------------------------------------
#define PIPE_STEP(BUF)                                                        \
  {                                                                          \
    asm volatile("s_waitcnt vmcnt(4) lgkmcnt(0)" ::: "memory");              \
    __builtin_amdgcn_s_barrier();                                            \
    __builtin_amdgcn_sched_barrier(0);                                       \
    stage((((BUF) + 2) % 3), (tile + 2) * 32);                               \
    compute(BUF);                                                            \
    ++tile;                                                                  \
  }

#define PIPE_TAIL()                                                          \
  asm volatile("s_waitcnt vmcnt(4) lgkmcnt(0)" ::: "memory");                \
  __builtin_amdgcn_s_barrier();                                              \
  __builtin_amdgcn_sched_barrier(0);                                         \
  compute(0); /* tile 30 */                                                  \
  asm volatile("s_waitcnt vmcnt(0) lgkmcnt(0)" ::: "memory");                \
  __builtin_amdgcn_s_barrier();                                              \
  __builtin_amdgcn_sched_barrier(0);                                         \
  compute(1); /* tile 31 */

// Fused Q/K/V projection. blockIdx.x 0..7 -> Q, 8..15 -> K, 16..23 -> V.
__global__ __launch_bounds__(256) void gemm_qkv(
    const short* __restrict__ A,
    const short* __restrict__ W0, const short* __restrict__ W1, const short* __restrict__ W2,
    const float* __restrict__ b0, const float* __restrict__ b1, const float* __restrict__ b2,
    float* __restrict__ kf, float* __restrict__ vf,
    short* __restrict__ qbo, short* __restrict__ kbo, short* __restrict__ vtbo) {
  __shared__ short SM[24576];                              // 48 KB: A bufs 0..2, B bufs 0..2
  const int t = threadIdx.x;
  const int lane = t & 63;
  const int w = t >> 6;
  const int wm = w >> 1, wn = w & 1;
  const int quad = lane >> 4, l15 = lane & 15;
  const int bm = blockIdx.y;
  const int sel = blockIdx.x >> 3, bn = blockIdx.x & 7;    // block-uniform branch
  const short* Bm = sel == 0 ? W0 : (sel == 1 ? W1 : W2);
  const float* bias = sel == 0 ? b0 : (sel == 1 ? b1 : b2);

  f32x4 acc[4][4];
  for (int i = 0; i < 4; i++)
    for (int j = 0; j < 4; j++) acc[i][j] = (f32x4){0.f, 0.f, 0.f, 0.f};

  const int c0 = t, c1 = t + 256;
  const int r0 = c0 >> 2, cc0 = c0 & 3;
  const int r1 = c1 >> 2, cc1 = c1 & 3;
  const short* Abase = A + (size_t)bm * 128 * 1024;
  const short* Bbase = Bm + (size_t)bn * 128 * 1024;

  auto stage = [&](int buf, int kk) {
    short* A_ = SM + buf * 4096;
    short* B_ = SM + 12288 + buf * 4096;
    GLDS16(Abase + (size_t)r0 * 1024 + kk + cc0 * 8, A_ + c0 * 8);
    GLDS16(Abase + (size_t)r1 * 1024 + kk + cc1 * 8, A_ + c1 * 8);
    GLDS16(Bbase + (size_t)r0 * 1024 + kk + cc0 * 8, B_ + c0 * 8);
    GLDS16(Bbase + (size_t)r1 * 1024 + kk + cc1 * 8, B_ + c1 * 8);
  };
  auto compute = [&](int buf) {
    const short* A_ = SM + buf * 4096;
    const short* B_ = SM + 12288 + buf * 4096;
    bf16x8 af[4], bfr[4];
    for (int mt = 0; mt < 4; mt++)
      af[mt] = *(const bf16x8*)(A_ + (wm * 64 + mt * 16 + l15) * 32 + quad * 8);
    for (int nt = 0; nt < 4; nt++)
      bfr[nt] = *(const bf16x8*)(B_ + (wn * 64 + nt * 16 + l15) * 32 + quad * 8);
    for (int mt = 0; mt < 4; mt++)
      for (int nt = 0; nt < 4; nt++)
        acc[mt][nt] = __builtin_amdgcn_mfma_f32_16x16x32_bf16(af[mt], bfr[nt], acc[mt][nt], 0, 0, 0);
  };

  stage(0, 0);
  stage(1, 32);
  int tile = 0;
  for (int ii = 0; ii < 10; ++ii) {      // tiles 0..29; stages tiles 2..31
    PIPE_STEP(0) PIPE_STEP(1) PIPE_STEP(2)
  }
  PIPE_TAIL()                             // tiles 30, 31

  if (sel != 2) {
    for (int mt = 0; mt < 4; mt++) {
      const int row_base = bm * 128 + wm * 64 + mt * 16 + quad * 4;
      for (int nt = 0; nt < 4; nt++) {
        const int col = bn * 128 + wn * 64 + nt * 16 + l15;
        const float bb = bias[col];
        for (int r = 0; r < 4; r++) {
          const int row = row_base + r;
          const float v = acc[mt][nt][r] + bb;
          const int b = row >> 11, tt = row & 2047;
          const int h = col >> 6, hi = col & 63;
          const size_t idx = (((size_t)(b * 16 + h)) * 2048 + tt) * 64 + hi;
          if (sel == 0) {
            qbo[idx] = f2b(v);
          } else {
            kf[idx] = v; kbo[idx] = f2b(v);
          }
        }
      }
    }
  } else {
    // V path: f32 out direct; bf16 transpose via LDS (stride 136 shorts).
    short* Tr = SM;                       // 128*136*2 = 34816 B <= 48 KB
    __syncthreads();
    for (int mt = 0; mt < 4; mt++) {
      const int rowb = wm * 64 + mt * 16 + quad * 4;     // local row base
      const int growb = bm * 128 + rowb;
      const int b_ = growb >> 11;
      for (int nt = 0; nt < 4; nt++) {
        const int colL = wn * 64 + nt * 16 + l15;
        const int col = bn * 128 + colL;
        const float bb = bias[col];
        const int h_ = col >> 6, hi_ = col & 63;
        short4 pk;
        for (int r = 0; r < 4; r++) {
          const float v = acc[mt][nt][r] + bb;
          const int tt = (growb + r) & 2047;
          vf[(((size_t)(b_ * 16 + h_)) * 2048 + tt) * 64 + hi_] = v;
          ((short*)&pk)[r] = f2b(v);
        }
        *(short4*)&Tr[colL * 136 + rowb] = pk;
      }
    }
    __syncthreads();
    const int c = t & 127, half = t >> 7;
    const int gcol = bn * 128 + c;
    const int h_ = gcol >> 6, hi_ = gcol & 63;
    for (int j = 0; j < 8; j++) {
      const int chunk = half * 8 + j;
      const int row0 = bm * 128 + chunk * 8;
      const int b_ = row0 >> 11, tt = row0 & 2047;
      bf16x8 val = *(const bf16x8*)&Tr[c * 136 + chunk * 8];
      *(bf16x8*)&vtbo[(((size_t)(b_ * 16 + h_)) * 64 + hi_) * 2048 + tt] = val;
    }
  }
}

// Output projection: C[8192][1024] = attb @ Wo^T + bo, same T4 pipeline.
__global__ __launch_bounds__(256) void gemm_o(
    const short* __restrict__ A, const short* __restrict__ Bm,
    const float* __restrict__ bias, float* __restrict__ out_f) {
  __shared__ short SM[24576];
  const int t = threadIdx.x;
  const int lane = t & 63;
  const int w = t >> 6;
  const int wm = w >> 1, wn = w & 1;
  const int quad = lane >> 4, l15 = lane & 15;
  const int bm = blockIdx.y, bn = blockIdx.x;

  f32x4 acc[4][4];
  for (int i = 0; i < 4; i++)
    for (int j = 0; j < 4; j++) acc[i][j] = (f32x4){0.f, 0.f, 0.f, 0.f};

  const int c0 = t, c1 = t + 256;
  const int r0 = c0 >> 2, cc0 = c0 & 3;
  const int r1 = c1 >> 2, cc1 = c1 & 3;
  const short* Abase = A + (size_t)bm * 128 * 1024;
  const short* Bbase = Bm + (size_t)bn * 128 * 1024;

  auto stage = [&](int buf, int kk) {
    short* A_ = SM + buf * 4096;
    short* B_ = SM + 12288 + buf * 4096;
    GLDS16(Abase + (size_t)r0 * 1024 + kk + cc0 * 8, A_ + c0 * 8);
    GLDS16(Abase + (size_t)r1 * 1024 + kk + cc1 * 8, A_ + c1 * 8);
    GLDS16(Bbase + (size_t)r0 * 1024 + kk + cc0 * 8, B_ + c0 * 8);
    GLDS16(Bbase + (size_t)r1 * 1024 + kk + cc1 * 8, B_ + c1 * 8);
  };
  auto compute = [&](int buf) {
    const short* A_ = SM + buf * 4096;
    const short* B_ = SM + 12288 + buf * 4096;
    bf16x8 af[4], bfr[4];
    for (int mt = 0; mt < 4; mt++)
      af[mt] = *(const bf16x8*)(A_ + (wm * 64 + mt * 16 + l15) * 32 + quad * 8);
    for (int nt = 0; nt < 4; nt++)
      bfr[nt] = *(const bf16x8*)(B_ + (wn * 64 + nt * 16 + l15) * 32 + quad * 8);
    for (int mt = 0; mt < 4; mt++)
      for (int nt = 0; nt < 4; nt++)
        acc[mt][nt] = __builtin_amdgcn_mfma_f32_16x16x32_bf16(af[mt], bfr[nt], acc[mt][nt], 0, 0, 0);
  };

  stage(0, 0);
  stage(1, 32);
  int tile = 0;
  for (int ii = 0; ii < 10; ++ii) {
    PIPE_STEP(0) PIPE_STEP(1) PIPE_STEP(2)
  }
  PIPE_TAIL()

  for (int mt = 0; mt < 4; mt++) {
    const int row_base = bm * 128 + wm * 64 + mt * 16 + quad * 4;
    for (int nt = 0; nt < 4; nt++) {
      const int col = bn * 128 + wn * 64 + nt * 16 + l15;
      const float bb = bias[col];
      for (int r = 0; r < 4; r++) {
        const int row = row_base + r;
        out_f[(size_t)row * 1024 + col] = acc[mt][nt][r] + bb;
      }
    }
  }
}

// Flash attention, S^T form. Round-5 changes:
//  * Split K/V staging waits (T4/FIFO vmcnt): issue K loads then V loads;
//    wait vmcnt(4) (K landed, V in flight) before QK^T; drain vmcnt(0) only
//    right before PV. V's 16 KB staging hides under QK+softmax. Requires raw
//    s_barrier (NOT __syncthreads, which drains vmcnt(0)) + sched_barrier(0)
//    fences at every crossing (round-3 hardening discipline).
//  * Coalesced O epilogue: bounce o through the wave-private Pd region
//    (16 ds_write_b16 + 2 ds_read_b128 + 2 b128 global stores per lane)
//    instead of 16 scattered 2B stores -> kills L2 write-allocate
//    (WRITE_SIZE was 4.5x ideal, +17 MB of RMW fetch).
// Unchanged: paired causal strips (17 tiles/block, 1024 uniform blocks),
// P-overlay of Ks, RAW-score softmax, exact defer-rescale, XCD head remap.
__global__ __launch_bounds__(256, 4) void attn_fwd(
    const short* __restrict__ Qb, const short* __restrict__ Kb,
    const short* __restrict__ VTb, short* __restrict__ Ob) {
  __shared__ short Ks[128 * 64];        // 16 KB; doubles as per-wave P after QK barrier
  __shared__ short VTs[64 * 128];       // 16 KB
  const int t = threadIdx.x;
  const int w = t >> 6;
  const int lane = t & 63;
  const int quad = lane >> 4, l15 = lane & 15;

  const int L = blockIdx.x + (blockIdx.y << 4);          // 0..1023
  const int work = ((L & 7) << 7) + (L >> 3);            // XCD k -> bh in [8k,8k+8)
  const int bh = work >> 4;
  const int base = work & 15;
  const int b = bh >> 4, h = bh & 15;

  const short* Qh = Qb + (size_t)bh * 2048 * 64;
  const short* Kh = Kb + (size_t)bh * 2048 * 64;
  const short* VTh = VTb + (size_t)bh * 64 * 2048;
  unsigned* Pd = (unsigned*)Ks + w * 1024;               // wave-private 4 KB
  const int swz = (l15 & 7) << 2;
  const float sscale = 0.125f * 1.4426950408889634f;     // hd^-0.5 * log2(e)

  for (int s = 0; s < 2; ++s) {
    const int qt = s ? (31 - base) : base;               // 17 tiles total per block
    const int q0 = qt * 64 + w * 16;
    const bf16x8 qf0 = *(const bf16x8*)(Qh + (q0 + l15) * 64 + quad * 8);
    const bf16x8 qf1 = *(const bf16x8*)(Qh + (q0 + l15) * 64 + quad * 8 + 32);

    float m_q = -1e30f, l_q = 0.f;
    f32x4 o[4];
    for (int nt = 0; nt < 4; nt++) o[nt] = (f32x4){0.f, 0.f, 0.f, 0.f};
    const int ntile = (qt >> 1) + 1;

    for (int jt = 0; jt < ntile; ++jt) {
      const int j0 = jt << 7;
      // (1) prev tile's PV readers (P in Ks, VTs) done; no vmcnt outstanding
      //     except this strip's Q loads (drained below as FIFO-oldest).
      __builtin_amdgcn_s_barrier();
      __builtin_amdgcn_sched_barrier(0);
      for (int rr = 0; rr < 4; rr++) {               // K: first 4 loads (FIFO-old)
        const int c = rr * 256 + t;
        const int row = c >> 3, colL = c & 7;
        const int colg = colL ^ (row & 7);
        GLDS16(Kh + (size_t)(j0 + row) * 64 + colg * 8, &Ks[c * 8]);
      }
      for (int rr = 0; rr < 4; rr++) {               // V: last 4 loads (FIFO-new)
        const int c = rr * 256 + t;
        const int row = c >> 4, colL = c & 15;
        const int colg = colL ^ (row & 7);
        GLDS16(VTh + (size_t)row * 2048 + j0 + colg * 8, &VTs[c * 8]);
      }
      // (2) K landed (mine: vmcnt<=4 leaves only V in flight); barrier = all
      asm volatile("s_waitcnt vmcnt(4)" ::: "memory");
      __builtin_amdgcn_s_barrier();
      __builtin_amdgcn_sched_barrier(0);

      float sv[8][4];    // RAW scores (scale folded into exp arg later)
      for (int si = 0; si < 8; ++si) {
        const int r = si * 16 + l15;
        bf16x8 kf0 = *(const bf16x8*)&Ks[(r * 8 + (quad ^ (r & 7))) * 8];
        bf16x8 kf1 = *(const bf16x8*)&Ks[(r * 8 + ((quad ^ 4) ^ (r & 7))) * 8];
        f32x4 z = (f32x4){0.f, 0.f, 0.f, 0.f};
        z = __builtin_amdgcn_mfma_f32_16x16x32_bf16(kf0, qf0, z, 0, 0, 0);
        z = __builtin_amdgcn_mfma_f32_16x16x32_bf16(kf1, qf1, z, 0, 0, 0);
        for (int r4 = 0; r4 < 4; r4++) sv[si][r4] = z[r4];
      }
      if (jt == ntile - 1) {                              // diagonal tile masks
        const int qg = q0 + l15;
        for (int si = 0; si < 8; si++) {
          const int kbase = j0 + si * 16 + quad * 4;
          for (int r4 = 0; r4 < 4; r4++)
            if (kbase + r4 > qg) sv[si][r4] = -1e30f;
        }
      }
      float vmax = fmaxf(fmaxf(sv[0][0], sv[0][1]), fmaxf(sv[0][2], sv[0][3]));
      for (int si = 1; si < 8; si++) {
        float m2 = fmaxf(fmaxf(sv[si][0], sv[si][1]), fmaxf(sv[si][2], sv[si][3]));
        vmax = fmaxf(vmax, m2);
      }
      vmax = fmaxf(vmax, __shfl_xor(vmax, 16));
      vmax = fmaxf(vmax, __shfl_xor(vmax, 32));
      const float mn = fmaxf(m_q, vmax);
      if (__any(vmax > m_q)) {           // exact skip: otherwise alpha==1 for all lanes
        const float alpha = __builtin_amdgcn_exp2f((m_q - mn) * sscale);
        l_q *= alpha;
        float ar[4];
        for (int r4 = 0; r4 < 4; r4++) ar[r4] = __shfl(alpha, quad * 4 + r4);
        for (int nt = 0; nt < 4; nt++)
          for (int r4 = 0; r4 < 4; r4++) o[nt][r4] *= ar[r4];
      }
      m_q = mn;
      // (3) all waves' QK reads of Ks done -> P overlay safe. Raw barrier:
      //     V loads stay in flight (the whole point).
      __builtin_amdgcn_s_barrier();
      __builtin_amdgcn_sched_barrier(0);

      const float negmns = -mn * sscale;
      float ssum = 0.f;
      for (int si = 0; si < 8; si++) {
        float p0 = __builtin_amdgcn_exp2f(fmaf(sv[si][0], sscale, negmns));
        float p1 = __builtin_amdgcn_exp2f(fmaf(sv[si][1], sscale, negmns));
        float p2 = __builtin_amdgcn_exp2f(fmaf(sv[si][2], sscale, negmns));
        float p3 = __builtin_amdgcn_exp2f(fmaf(sv[si][3], sscale, negmns));
        ssum += (p0 + p1) + (p2 + p3);
        uint2 pk; pk.x = cvtpk2(p0, p1); pk.y = cvtpk2(p2, p3);
        *(uint2*)(Pd + l15 * 64 + ((si * 8 + quad * 2) ^ swz)) = pk;
      }
      ssum += __shfl_xor(ssum, 16);
      ssum += __shfl_xor(ssum, 32);
      l_q += ssum;       // alpha already applied inside the rescale branch

      // (4) V landed (mine vmcnt(0)); barrier = all waves' V landed.
      asm volatile("s_waitcnt vmcnt(0)" ::: "memory");
      __builtin_amdgcn_s_barrier();
      __builtin_amdgcn_sched_barrier(0);

      for (int kc = 0; kc < 4; kc++) {
        bf16x8 pf = *(const bf16x8*)(Pd + l15 * 64 + ((kc * 16 + quad * 4) ^ swz));
        for (int nt = 0; nt < 4; nt++) {
          const int rv = nt * 16 + l15;
          bf16x8 vf = *(const bf16x8*)&VTs[(rv * 16 + ((kc * 4 + quad) ^ (rv & 7))) * 8];
          o[nt] = __builtin_amdgcn_mfma_f32_16x16x32_bf16(pf, vf, o[nt], 0, 0, 0);
        }
      }
    }

    // Coalesced O epilogue via wave-private LDS (Pd region, PV reads done).
    float lr[4], ri[4];
    for (int r4 = 0; r4 < 4; r4++) lr[r4] = __shfl(l_q, quad * 4 + r4);
    for (int r4 = 0; r4 < 4; r4++) ri[r4] = __builtin_amdgcn_rcpf(lr[r4]);
    short* Po = (short*)Pd;                            // 2 KB used of 4 KB
    for (int nt = 0; nt < 4; nt++)
      for (int r4 = 0; r4 < 4; r4++)
        Po[(quad * 4 + r4) * 64 + nt * 16 + l15] = f2b(o[nt][r4] * ri[r4]);
    asm volatile("s_waitcnt lgkmcnt(0)" ::: "memory");
    __builtin_amdgcn_sched_barrier(0);
    for (int k2 = 0; k2 < 2; k2++) {
      const int F = lane + 64 * k2;
      const int R = F >> 3, c = F & 7;                 // 16 rows x 8 chunks
      bf16x8 val = *(const bf16x8*)&Po[R * 64 + c * 8];
      *(bf16x8*)&Ob[((size_t)(b * 2048 + q0 + R)) * 1024 + h * 64 + c * 8] = val;
    }
  }
}

extern "C" void kernel_launch(void* const* d_in, const int* in_sizes, int n_in,
                              void* d_out, int out_size, void* d_ws, size_t ws_size,
                              hipStream_t stream) {
  const float* x  = (const float*)d_in[0];
  const float* Wq = (const float*)d_in[1];
  const float* bq = (const float*)d_in[2];
  const float* Wk = (const float*)d_in[3];
  const float* bk = (const float*)d_in[4];
  const float* Wv = (const float*)d_in[5];
  const float* bv = (const float*)d_in[6];
  const float* Wo = (const float*)d_in[7];
  const float* bo = (const float*)d_in[8];

  float* out   = (float*)d_out;
  float* k_out = out + (size_t)8388608;
  float* v_out = out + (size_t)16777216;

  short* ws  = (short*)d_ws;
  short* xb   = ws;                    // 8388608 elems
  short* wqb  = ws + 8388608;          // 1048576 (wq,wk,wv,wo contiguous)
  short* wkb  = ws + 9437184;
  short* wvb  = ws + 10485760;
  short* wob  = ws + 11534336;
  short* qb   = ws + 12582912;         // 8388608 [B,H,T,64]
  short* kb   = ws + 20971520;         // 8388608 [B,H,T,64]
  short* vtb  = ws + 29360128;         // 8388608 [B,H,64,T]
  short* attb = ws + 37748736;         // 8388608 [B*T,1024]

  cvt_f32_bf16<<<8192, 256, 0, stream>>>(x, xb, 2097152);
  cvt_w4<<<4096, 256, 0, stream>>>(Wq, Wk, Wv, Wo, wqb);

  gemm_qkv<<<dim3(24, 64), 256, 0, stream>>>(
      xb, wqb, wkb, wvb, bq, bk, bv, k_out, v_out, qb, kb, vtb);

  attn_fwd<<<dim3(16, 64), 256, 0, stream>>>(qb, kb, vtb, attb);

  gemm_o<<<dim3(8, 64), 256, 0, stream>>>(attb, wob, bo, out);
}